// Round 6
// baseline (168.335 us; speedup 1.0000x reference)
//
#include <hip/hip_runtime.h>
#include <hip/hip_fp16.h>
#include <math.h>

// D3 constants
#define K1C 16.0f
#define K2C (4.0f / 3.0f)
#define K3C 4.0f
#define A1C 0.4f
#define A2C 5.0f
#define S6C 1.0f
#define S8C 0.78f
#define CN_CUT 25.0f
#define DISP_CUT 50.0f
#define MAXZ 95
#define NREF 5
#define THS 32        // fp16 table panel stride in halves (64 bytes)
#define NB 9216       // sort bins (>= 95*95 = 9025)
#define SORTB 128     // sort blocks
#define SORTT 512     // sort threads per block

typedef float f4 __attribute__((ext_vector_type(4)));

__device__ __forceinline__ unsigned h2bits(__half2 h) {
    union { __half2 h; unsigned u; } c; c.h = h; return c.u;
}
__device__ __forceinline__ float2 bits2f2(unsigned u) {
    union { unsigned u; __half2 h; } c; c.u = u; return __half22float2(c.h);
}

// ---------------- Kernel 0: pack posrec + fp16 table ----------------
__global__ void pack_kernel(const float* __restrict__ pos,
                            const int* __restrict__ numbers,
                            const float* __restrict__ rcov,
                            const float* __restrict__ c6tab,
                            f4* __restrict__ posrec,
                            unsigned* __restrict__ tabh,
                            int n_atoms) {
    int t = blockIdx.x * blockDim.x + threadIdx.x;
    int stride = gridDim.x * blockDim.x;
    const int ntab = MAXZ * MAXZ;
    for (int p = t; p < ntab; p += stride) {
        const float* src = c6tab + (size_t)p * 25;
        float v[32];
#pragma unroll
        for (int k = 0; k < 25; ++k) v[k] = src[k];
#pragma unroll
        for (int k = 25; k < 32; ++k) v[k] = 0.0f;
        unsigned u[16];
#pragma unroll
        for (int k = 0; k < 16; ++k) u[k] = h2bits(__floats2half2_rn(v[2 * k], v[2 * k + 1]));
        uint4* dst = (uint4*)(tabh + (size_t)p * (THS / 2));
        uint4 d0 = { u[0], u[1], u[2], u[3] };
        uint4 d1 = { u[4], u[5], u[6], u[7] };
        uint4 d2 = { u[8], u[9], u[10], u[11] };
        uint4 d3 = { u[12], u[13], u[14], u[15] };
        dst[0] = d0; dst[1] = d1; dst[2] = d2; dst[3] = d3;
    }
    for (int a = t; a < n_atoms; a += stride) {
        int z = numbers[a];
        f4 r = { pos[3 * a + 0], pos[3 * a + 1], pos[3 * a + 2], rcov[z] };
        posrec[a] = r;
    }
}

// ---------------- Kernel 1: fused CN scatter-add + 8B edge record (R4-exact) ----------------
__global__ void cn_pre_kernel(const f4* __restrict__ posrec,
                              const int* __restrict__ ei,
                              const int* __restrict__ ej,
                              float* __restrict__ cn,
                              uint2* __restrict__ d_ij,
                              int n_edges) {
    int t = blockIdx.x * blockDim.x + threadIdx.x;
    int lane = threadIdx.x & 63;
    int gwave = t >> 6;
    int nwave = (gridDim.x * blockDim.x) >> 6;
    for (int wb = gwave * 256; wb < n_edges; wb += nwave * 256) {
        int e0 = wb + lane;
        int idx[4], jdx[4];
        bool ok[4];
        f4 pa[4], pb[4];
#pragma unroll
        for (int s = 0; s < 4; ++s) {
            int e = e0 + s * 64;
            ok[s] = (e < n_edges);
            idx[s] = ok[s] ? ei[e] : 0;
            jdx[s] = ok[s] ? ej[e] : 0;
        }
#pragma unroll
        for (int s = 0; s < 4; ++s) { pa[s] = posrec[idx[s]]; pb[s] = posrec[jdx[s]]; }
#pragma unroll
        for (int s = 0; s < 4; ++s) {
            int e = e0 + s * 64;
            float dx = pb[s].x - pa[s].x;
            float dy = pb[s].y - pa[s].y;
            float dz = pb[s].z - pa[s].z;
            float d = sqrtf(dx * dx + dy * dy + dz * dz + 1e-20f);
            if (ok[s]) {
                if (d < CN_CUT) {
                    float rr = pa[s].w + pb[s].w;
                    float x = K1C * (K2C * rr / d - 1.0f);
                    atomicAdd(&cn[idx[s]], 1.0f / (1.0f + expf(-x)));
                }
                uint2 r;
                r.x = __float_as_uint(d);
                r.y = (unsigned)idx[s] | ((unsigned)jdx[s] << 16);
                d_ij[e] = r;
            }
        }
    }
}

// ---------------- Kernel 2: per-atom weight record ----------------
__global__ void weights_kernel(const float* __restrict__ cn,
                               const int* __restrict__ numbers,
                               const float* __restrict__ cn_ref,
                               const float* __restrict__ r4r2,
                               uint4* __restrict__ wrec,
                               int n_atoms) {
    int stride = gridDim.x * blockDim.x;
    for (int a = blockIdx.x * blockDim.x + threadIdx.x; a < n_atoms; a += stride) {
        int z = numbers[a];
        float c = cn[a];
        float gw[NREF];
        float norm = 0.0f;
        float best = -INFINITY;
        int bi = 0;
#pragma unroll
        for (int m = 0; m < NREF; ++m) {
            float r = cn_ref[z * NREF + m];
            bool valid = (r >= 0.0f);
            float tt = c - r;
            float g = valid ? expf(-K3C * tt * tt) : 0.0f;
            gw[m] = g;
            norm += g;
            if (valid && r > best) { best = r; bi = m; }
        }
        float out[NREF];
        if (norm > 1e-30f) {
            float inv = 1.0f / norm;
#pragma unroll
            for (int m = 0; m < NREF; ++m) out[m] = gw[m] * inv;
        } else {
#pragma unroll
            for (int m = 0; m < NREF; ++m) out[m] = (m == bi) ? 1.0f : 0.0f;
        }
        uint4 r;
        r.x = h2bits(__floats2half2_rn(out[0], out[1]));
        r.y = h2bits(__floats2half2_rn(out[2], out[3]));
        r.z = __float_as_uint(r4r2[z]);
        r.w = (unsigned)z;
        wrec[a] = r;
    }
}

// ---------------- Sort kernel A: per-block LDS histogram + pidx stream ----------------
__global__ __launch_bounds__(SORTT) void hist_kernel(const uint2* __restrict__ d_ij,
                                                     const uint4* __restrict__ wrec,
                                                     unsigned short* __restrict__ pidx16,
                                                     unsigned* __restrict__ g_hist,
                                                     int n_edges, int epb) {
    __shared__ unsigned h[NB];
    for (int b = threadIdx.x; b < NB; b += blockDim.x) h[b] = 0u;
    __syncthreads();
    const unsigned* wrecw = (const unsigned*)wrec;
    int start = blockIdx.x * epb;
    int end = start + epb;
    if (end > n_edges) end = n_edges;
    for (int e = start + threadIdx.x; e < end; e += blockDim.x) {
        unsigned ij = d_ij[e].y;
        unsigned i = ij & 0xFFFFu;
        unsigned j = ij >> 16;
        unsigned zi = wrecw[4u * i + 3u];
        unsigned zj = wrecw[4u * j + 3u];
        unsigned p = zi * MAXZ + zj;
        pidx16[e] = (unsigned short)p;
        atomicAdd(&h[p], 1u);
    }
    __syncthreads();
    unsigned* row = g_hist + (size_t)blockIdx.x * NB;
    for (int b = threadIdx.x; b < NB; b += blockDim.x) row[b] = h[b];
}

// ---------------- Sort kernel B: block-exclusive prefix per bin + bin totals ----------------
__global__ void scan_kernel(unsigned* __restrict__ g_hist,
                            unsigned* __restrict__ bin_total) {
    int bin = blockIdx.x * blockDim.x + threadIdx.x;
    if (bin >= NB) return;
    unsigned run = 0;
    for (int b = 0; b < SORTB; ++b) {
        unsigned t = g_hist[(size_t)b * NB + bin];
        g_hist[(size_t)b * NB + bin] = run;
        run += t;
    }
    bin_total[bin] = run;
}

// ---------------- Sort kernel C: exclusive scan of bin totals (1 block, 1024 thr) ----------------
__global__ __launch_bounds__(1024) void prefix_kernel(const unsigned* __restrict__ bin_total,
                                                      unsigned* __restrict__ bin_base) {
    const int BPT = NB / 1024;  // 9
    int tid = threadIdx.x;
    unsigned v[BPT];
    unsigned sum = 0;
#pragma unroll
    for (int k = 0; k < BPT; ++k) {
        unsigned t = bin_total[tid * BPT + k];
        v[k] = sum;
        sum += t;
    }
    // inclusive wave scan of per-thread sums
    int lane = tid & 63;
    int wid = tid >> 6;
    unsigned s = sum;
#pragma unroll
    for (int d = 1; d < 64; d <<= 1) {
        unsigned t = __shfl_up(s, d, 64);
        if (lane >= d) s += t;
    }
    __shared__ unsigned wtot[16];
    if (lane == 63) wtot[wid] = s;
    __syncthreads();
    if (tid == 0) {
        unsigned r = 0;
        for (int w = 0; w < 16; ++w) { unsigned t = wtot[w]; wtot[w] = r; r += t; }
    }
    __syncthreads();
    unsigned excl = wtot[wid] + s - sum;  // exclusive prefix for this thread
#pragma unroll
    for (int k = 0; k < BPT; ++k) bin_base[tid * BPT + k] = excl + v[k];
}

// ---------------- Sort kernel D: scatter to sorted positions (no global atomics) ----------------
__global__ __launch_bounds__(SORTT) void scatter_kernel(const uint2* __restrict__ d_ij,
                                                        const unsigned short* __restrict__ pidx16,
                                                        const unsigned* __restrict__ g_hist,
                                                        const unsigned* __restrict__ bin_base,
                                                        uint2* __restrict__ sorted,
                                                        int n_edges, int epb) {
    __shared__ unsigned cur[NB];
    const unsigned* row = g_hist + (size_t)blockIdx.x * NB;
    for (int b = threadIdx.x; b < NB; b += blockDim.x) cur[b] = row[b] + bin_base[b];
    __syncthreads();
    int start = blockIdx.x * epb;
    int end = start + epb;
    if (end > n_edges) end = n_edges;
    for (int e = start + threadIdx.x; e < end; e += blockDim.x) {
        uint2 r = d_ij[e];
        unsigned p = pidx16[e];
        unsigned pos = atomicAdd(&cur[p], 1u);
        sorted[pos] = r;
    }
}

// ---------------- Kernel 3: pair energy + reduction (reads pidx-sorted records) ----------------
__global__ void energy_kernel(const uint2* __restrict__ edgerec,
                              const uint4* __restrict__ wrec,
                              const unsigned* __restrict__ tabh,
                              double* __restrict__ acc,
                              int n_edges) {
    double local = 0.0;
    int t = blockIdx.x * blockDim.x + threadIdx.x;
    int lane = threadIdx.x & 63;
    int gwave = t >> 6;
    int nwave = (gridDim.x * blockDim.x) >> 6;
    for (int wb = gwave * 256; wb < n_edges; wb += nwave * 256) {
        int e0 = wb + lane;
        uint2 rec[4];
        bool ok[4];
#pragma unroll
        for (int s = 0; s < 4; ++s) {
            int e = e0 + s * 64;
            ok[s] = (e < n_edges);
            uint2 dead = { __float_as_uint(1e30f), 0u };
            rec[s] = ok[s] ? edgerec[e] : dead;
        }
        uint4 wri[4], wrj[4];
#pragma unroll
        for (int s = 0; s < 4; ++s) {
            unsigned ij = rec[s].y;
            wri[s] = wrec[ij & 0xFFFFu];
            wrj[s] = wrec[ij >> 16];
        }
        uint4 t0[4], t1[4], t2[4];
        unsigned t3[4];
#pragma unroll
        for (int s = 0; s < 4; ++s) {
            int pidx = (int)wri[s].w * MAXZ + (int)wrj[s].w;
            const uint4* Tv = (const uint4*)(tabh + (size_t)pidx * (THS / 2));
            t0[s] = Tv[0];
            t1[s] = Tv[1];
            t2[s] = Tv[2];
            t3[s] = ((const unsigned*)Tv)[12];
        }
#pragma unroll
        for (int s = 0; s < 4; ++s) {
            float d = __uint_as_float(rec[s].x);
            if (d < DISP_CUT) {
                float wiv[NREF], wjv[NREF];
                float2 p;
                p = bits2f2(wri[s].x); wiv[0] = p.x; wiv[1] = p.y;
                p = bits2f2(wri[s].y); wiv[2] = p.x; wiv[3] = p.y;
                wiv[4] = 1.0f - (wiv[0] + wiv[1] + wiv[2] + wiv[3]);
                p = bits2f2(wrj[s].x); wjv[0] = p.x; wjv[1] = p.y;
                p = bits2f2(wrj[s].y); wjv[2] = p.x; wjv[3] = p.y;
                wjv[4] = 1.0f - (wjv[0] + wjv[1] + wjv[2] + wjv[3]);
                unsigned us[13] = { t0[s].x, t0[s].y, t0[s].z, t0[s].w,
                                    t1[s].x, t1[s].y, t1[s].z, t1[s].w,
                                    t2[s].x, t2[s].y, t2[s].z, t2[s].w, t3[s] };
                float tt[26];
#pragma unroll
                for (int k = 0; k < 13; ++k) {
                    float2 q = bits2f2(us[k]);
                    tt[2 * k] = q.x;
                    tt[2 * k + 1] = q.y;
                }
                float c6 = 0.0f;
#pragma unroll
                for (int a = 0; a < NREF; ++a) {
                    float sacc = 0.0f;
#pragma unroll
                    for (int b = 0; b < NREF; ++b) sacc += wjv[b] * tt[a * NREF + b];
                    c6 += wiv[a] * sacc;
                }
                float r4i = __uint_as_float(wri[s].z);
                float r4j = __uint_as_float(wrj[s].z);
                float qq = 3.0f * r4i * r4j;
                float c8 = c6 * qq;
                float f = A1C * sqrtf(qq) + A2C;
                float f2 = f * f;
                float f6 = f2 * f2 * f2;
                float f8 = f6 * f2;
                float d2 = d * d;
                float d6 = d2 * d2 * d2;
                float d8 = d6 * d2;
                float e_pair = -(S6C * c6 / (d6 + f6) + S8C * c8 / (d8 + f8));
                local += 0.5 * (double)e_pair;
            }
        }
    }
#pragma unroll
    for (int off = 32; off > 0; off >>= 1) local += __shfl_down(local, off, 64);
    __shared__ double wsum[8];
    int wave = threadIdx.x >> 6;
    if ((threadIdx.x & 63) == 0) wsum[wave] = local;
    __syncthreads();
    if (threadIdx.x == 0) {
        double b = 0.0;
        int nwaves = (blockDim.x + 63) >> 6;
        for (int w = 0; w < nwaves; ++w) b += wsum[w];
        atomicAdd(acc, b);
    }
}

// ---------------- Fallback (small ws or n_atoms > 65535) ----------------
__global__ void cn_kernel_old(const float* __restrict__ pos,
                              const int* __restrict__ numbers,
                              const int* __restrict__ ei,
                              const int* __restrict__ ej,
                              const float* __restrict__ rcov,
                              float* __restrict__ cn,
                              int n_edges) {
    int stride = gridDim.x * blockDim.x;
    for (int e = blockIdx.x * blockDim.x + threadIdx.x; e < n_edges; e += stride) {
        int i = ei[e];
        int j = ej[e];
        float dx = pos[3 * j + 0] - pos[3 * i + 0];
        float dy = pos[3 * j + 1] - pos[3 * i + 1];
        float dz = pos[3 * j + 2] - pos[3 * i + 2];
        float d = sqrtf(dx * dx + dy * dy + dz * dz + 1e-20f);
        if (d < CN_CUT) {
            float rr = rcov[numbers[i]] + rcov[numbers[j]];
            float x = K1C * (K2C * rr / d - 1.0f);
            atomicAdd(&cn[i], 1.0f / (1.0f + expf(-x)));
        }
    }
}

__global__ void energy_kernel_old(const float* __restrict__ pos,
                                  const int* __restrict__ ei,
                                  const int* __restrict__ ej,
                                  const float* __restrict__ c6tab,
                                  const uint4* __restrict__ wrec,
                                  double* __restrict__ acc,
                                  int n_edges) {
    double local = 0.0;
    int stride = gridDim.x * blockDim.x;
    for (int e = blockIdx.x * blockDim.x + threadIdx.x; e < n_edges; e += stride) {
        int i = ei[e];
        int j = ej[e];
        float dx = pos[3 * j + 0] - pos[3 * i + 0];
        float dy = pos[3 * j + 1] - pos[3 * i + 1];
        float dz = pos[3 * j + 2] - pos[3 * i + 2];
        float d = sqrtf(dx * dx + dy * dy + dz * dz + 1e-20f);
        if (d < DISP_CUT) {
            uint4 wi = wrec[i], wj = wrec[j];
            int zi = (int)wi.w, zj = (int)wj.w;
            const float* T = c6tab + ((size_t)(zi * MAXZ + zj)) * 25;
            float wiv[NREF], wjv[NREF];
            float2 p;
            p = bits2f2(wi.x); wiv[0] = p.x; wiv[1] = p.y;
            p = bits2f2(wi.y); wiv[2] = p.x; wiv[3] = p.y;
            wiv[4] = 1.0f - (wiv[0] + wiv[1] + wiv[2] + wiv[3]);
            p = bits2f2(wj.x); wjv[0] = p.x; wjv[1] = p.y;
            p = bits2f2(wj.y); wjv[2] = p.x; wjv[3] = p.y;
            wjv[4] = 1.0f - (wjv[0] + wjv[1] + wjv[2] + wjv[3]);
            float c6 = 0.0f;
#pragma unroll
            for (int a = 0; a < NREF; ++a) {
                float sacc = 0.0f;
#pragma unroll
                for (int b = 0; b < NREF; ++b) sacc += wjv[b] * T[a * NREF + b];
                c6 += wiv[a] * sacc;
            }
            float qq = 3.0f * __uint_as_float(wi.z) * __uint_as_float(wj.z);
            float c8 = c6 * qq;
            float f = A1C * sqrtf(qq) + A2C;
            float f2 = f * f;
            float f6 = f2 * f2 * f2;
            float f8 = f6 * f2;
            float d2 = d * d;
            float d6 = d2 * d2 * d2;
            float d8 = d6 * d2;
            float e_pair = -(S6C * c6 / (d6 + f6) + S8C * c8 / (d8 + f8));
            local += 0.5 * (double)e_pair;
        }
    }
#pragma unroll
    for (int off = 32; off > 0; off >>= 1) local += __shfl_down(local, off, 64);
    __shared__ double wsum[8];
    int wave = threadIdx.x >> 6;
    if ((threadIdx.x & 63) == 0) wsum[wave] = local;
    __syncthreads();
    if (threadIdx.x == 0) {
        double b = 0.0;
        int nwaves = (blockDim.x + 63) >> 6;
        for (int w = 0; w < nwaves; ++w) b += wsum[w];
        atomicAdd(acc, b);
    }
}

// ---------------- finalize ----------------
__global__ void finalize_kernel(const double* __restrict__ acc, float* __restrict__ out) {
    out[0] = (float)acc[0];
}

static inline size_t align16(size_t x) { return (x + 15) & ~(size_t)15; }

extern "C" void kernel_launch(void* const* d_in, const int* in_sizes, int n_in,
                              void* d_out, int out_size, void* d_ws, size_t ws_size,
                              hipStream_t stream) {
    const float* pos     = (const float*)d_in[0];
    const int*   numbers = (const int*)d_in[1];
    const int*   ei      = (const int*)d_in[2];
    const int*   ej      = (const int*)d_in[3];
    const float* rcov    = (const float*)d_in[4];
    const float* r4r2    = (const float*)d_in[5];
    const float* c6tab   = (const float*)d_in[6];
    const float* cn_ref  = (const float*)d_in[7];

    int n_atoms = in_sizes[1];
    int n_edges = in_sizes[2];

    char* ws = (char*)d_ws;
    size_t off = 0;
    float* cn = (float*)(ws + off);          off += align16((size_t)n_atoms * 4);
    double* acc = (double*)(ws + off);       size_t zero_bytes = off + 16; off += 16;
    uint4* wrec = (uint4*)(ws + off);        off += (size_t)n_atoms * 16;
    size_t small_needed = off;
    f4* posrec = (f4*)(ws + off);            off += (size_t)n_atoms * 16;
    unsigned* tabh = (unsigned*)(ws + off);  off += align16((size_t)MAXZ * MAXZ * (THS / 2) * 4);
    uint2* d_ij = (uint2*)(ws + off);        off += (size_t)n_edges * 8;
    size_t mid_needed = off;
    unsigned short* pidx16 = (unsigned short*)(ws + off); off += align16((size_t)n_edges * 2);
    uint2* sorted = (uint2*)(ws + off);      off += (size_t)n_edges * 8;
    unsigned* g_hist = (unsigned*)(ws + off); off += (size_t)SORTB * NB * 4;
    unsigned* bin_total = (unsigned*)(ws + off); off += (size_t)NB * 4;
    unsigned* bin_base = (unsigned*)(ws + off);  off += (size_t)NB * 4;
    size_t full_needed = off;

    hipMemsetAsync(d_ws, 0, zero_bytes, stream);

    const int block = 256;
    int egrid = (n_edges + block - 1) / block;
    int egrid4 = (n_edges + block * 4 - 1) / (block * 4);
    int agrid = (n_atoms + block - 1) / block;
    int pgrid = ((MAXZ * MAXZ > n_atoms ? MAXZ * MAXZ : n_atoms) + block - 1) / block;
    int epb = (n_edges + SORTB - 1) / SORTB;

    if (ws_size >= full_needed && n_atoms <= 65535) {
        pack_kernel<<<pgrid, block, 0, stream>>>(pos, numbers, rcov, c6tab,
                                                 posrec, tabh, n_atoms);
        cn_pre_kernel<<<egrid4, block, 0, stream>>>(posrec, ei, ej, cn, d_ij, n_edges);
        weights_kernel<<<agrid, block, 0, stream>>>(cn, numbers, cn_ref, r4r2, wrec, n_atoms);
        hist_kernel<<<SORTB, SORTT, 0, stream>>>(d_ij, wrec, pidx16, g_hist, n_edges, epb);
        scan_kernel<<<(NB + 255) / 256, 256, 0, stream>>>(g_hist, bin_total);
        prefix_kernel<<<1, 1024, 0, stream>>>(bin_total, bin_base);
        scatter_kernel<<<SORTB, SORTT, 0, stream>>>(d_ij, pidx16, g_hist, bin_base,
                                                    sorted, n_edges, epb);
        energy_kernel<<<egrid4, block, 0, stream>>>(sorted, wrec, tabh, acc, n_edges);
    } else if (ws_size >= mid_needed && n_atoms <= 65535) {
        pack_kernel<<<pgrid, block, 0, stream>>>(pos, numbers, rcov, c6tab,
                                                 posrec, tabh, n_atoms);
        cn_pre_kernel<<<egrid4, block, 0, stream>>>(posrec, ei, ej, cn, d_ij, n_edges);
        weights_kernel<<<agrid, block, 0, stream>>>(cn, numbers, cn_ref, r4r2, wrec, n_atoms);
        energy_kernel<<<egrid4, block, 0, stream>>>(d_ij, wrec, tabh, acc, n_edges);
    } else if (ws_size >= small_needed) {
        cn_kernel_old<<<egrid, block, 0, stream>>>(pos, numbers, ei, ej, rcov, cn, n_edges);
        weights_kernel<<<agrid, block, 0, stream>>>(cn, numbers, cn_ref, r4r2, wrec, n_atoms);
        energy_kernel_old<<<egrid, block, 0, stream>>>(pos, ei, ej, c6tab, wrec, acc, n_edges);
    }
    finalize_kernel<<<1, 1, 0, stream>>>(acc, (float*)d_out);
}

// Round 7
// 123.078 us; speedup vs baseline: 1.3677x; 1.3677x over previous
//
#include <hip/hip_runtime.h>
#include <hip/hip_fp16.h>
#include <math.h>

// D3 constants
#define K1C 16.0f
#define K2C (4.0f / 3.0f)
#define K3C 4.0f
#define A1C 0.4f
#define A2C 5.0f
#define S6C 1.0f
#define S8C 0.78f
#define CN_CUT 25.0f
#define DISP_CUT 50.0f
#define MAXZ 95
#define NREF 5
#define THS 32        // fp16 table panel stride in halves (64 bytes)
#define NCN 4         // CN accumulator copies (atomic contention split)

typedef float f4 __attribute__((ext_vector_type(4)));

__device__ __forceinline__ unsigned h2bits(__half2 h) {
    union { __half2 h; unsigned u; } c; c.h = h; return c.u;
}
__device__ __forceinline__ float2 bits2f2(unsigned u) {
    union { unsigned u; __half2 h; } c; c.u = u; return __half22float2(c.h);
}

// ---------------- Kernel 0: pack posrec + fp16 table ----------------
// posrec[a] = {x, y, z, rcov[za] + 4*za}   (z recoverable: floor(w/4), rcov in (1,3))
__global__ void pack_kernel(const float* __restrict__ pos,
                            const int* __restrict__ numbers,
                            const float* __restrict__ rcov,
                            const float* __restrict__ c6tab,
                            f4* __restrict__ posrec,
                            unsigned* __restrict__ tabh,
                            int n_atoms) {
    int t = blockIdx.x * blockDim.x + threadIdx.x;
    int stride = gridDim.x * blockDim.x;
    const int ntab = MAXZ * MAXZ;
    for (int p = t; p < ntab; p += stride) {
        const float* src = c6tab + (size_t)p * 25;
        float v[32];
#pragma unroll
        for (int k = 0; k < 25; ++k) v[k] = src[k];
#pragma unroll
        for (int k = 25; k < 32; ++k) v[k] = 0.0f;
        unsigned u[16];
#pragma unroll
        for (int k = 0; k < 16; ++k) u[k] = h2bits(__floats2half2_rn(v[2 * k], v[2 * k + 1]));
        uint4* dst = (uint4*)(tabh + (size_t)p * (THS / 2));
        uint4 d0 = { u[0], u[1], u[2], u[3] };
        uint4 d1 = { u[4], u[5], u[6], u[7] };
        uint4 d2 = { u[8], u[9], u[10], u[11] };
        uint4 d3 = { u[12], u[13], u[14], u[15] };
        dst[0] = d0; dst[1] = d1; dst[2] = d2; dst[3] = d3;
    }
    for (int a = t; a < n_atoms; a += stride) {
        int z = numbers[a];
        f4 r = { pos[3 * a + 0], pos[3 * a + 1], pos[3 * a + 2],
                 rcov[z] + 4.0f * (float)z };
        posrec[a] = r;
    }
}

// ---------------- Kernel 1: fused CN scatter-add + 16B edge record ----------------
// erec[e] = {bits(d), i | j<<16, pidx, 0}
__global__ void cn_pre_kernel(const f4* __restrict__ posrec,
                              const int* __restrict__ ei,
                              const int* __restrict__ ej,
                              float* __restrict__ cn4,   // NCN copies, stride npad
                              uint4* __restrict__ erec,
                              int n_edges, int npad) {
    int t = blockIdx.x * blockDim.x + threadIdx.x;
    int lane = threadIdx.x & 63;
    int gwave = t >> 6;
    int nwave = (gridDim.x * blockDim.x) >> 6;
    float* cnc = cn4 + (size_t)(blockIdx.x & (NCN - 1)) * npad;
    for (int wb = gwave * 256; wb < n_edges; wb += nwave * 256) {
        int e0 = wb + lane;
        int idx[4], jdx[4];
        bool ok[4];
        f4 pa[4], pb[4];
#pragma unroll
        for (int s = 0; s < 4; ++s) {
            int e = e0 + s * 64;
            ok[s] = (e < n_edges);
            idx[s] = ok[s] ? ei[e] : 0;
            jdx[s] = ok[s] ? ej[e] : 0;
        }
#pragma unroll
        for (int s = 0; s < 4; ++s) { pa[s] = posrec[idx[s]]; pb[s] = posrec[jdx[s]]; }
#pragma unroll
        for (int s = 0; s < 4; ++s) {
            int e = e0 + s * 64;
            float dx = pb[s].x - pa[s].x;
            float dy = pb[s].y - pa[s].y;
            float dz = pb[s].z - pa[s].z;
            float d = sqrtf(dx * dx + dy * dy + dz * dz + 1e-20f);
            int zi = (int)floorf(pa[s].w * 0.25f);
            int zj = (int)floorf(pb[s].w * 0.25f);
            float rci = pa[s].w - 4.0f * (float)zi;
            float rcj = pb[s].w - 4.0f * (float)zj;
            if (ok[s]) {
                if (d < CN_CUT) {
                    float rr = rci + rcj;
                    float x = K1C * (K2C * rr / d - 1.0f);
                    atomicAdd(&cnc[idx[s]], 1.0f / (1.0f + expf(-x)));
                }
                uint4 r;
                r.x = __float_as_uint(d);
                r.y = (unsigned)idx[s] | ((unsigned)jdx[s] << 16);
                r.z = (unsigned)(zi * MAXZ + zj);
                r.w = 0u;
                erec[e] = r;
            }
        }
    }
}

// ---------------- Kernel 2: per-atom weight record ----------------
__global__ void weights_kernel(const float* __restrict__ cn4,
                               const int* __restrict__ numbers,
                               const float* __restrict__ cn_ref,
                               const float* __restrict__ r4r2,
                               uint4* __restrict__ wrec,
                               int n_atoms, int npad) {
    int stride = gridDim.x * blockDim.x;
    for (int a = blockIdx.x * blockDim.x + threadIdx.x; a < n_atoms; a += stride) {
        int z = numbers[a];
        float c = 0.0f;
#pragma unroll
        for (int k = 0; k < NCN; ++k) c += cn4[(size_t)k * npad + a];
        float gw[NREF];
        float norm = 0.0f;
        float best = -INFINITY;
        int bi = 0;
#pragma unroll
        for (int m = 0; m < NREF; ++m) {
            float r = cn_ref[z * NREF + m];
            bool valid = (r >= 0.0f);
            float tt = c - r;
            float g = valid ? expf(-K3C * tt * tt) : 0.0f;
            gw[m] = g;
            norm += g;
            if (valid && r > best) { best = r; bi = m; }
        }
        float out[NREF];
        if (norm > 1e-30f) {
            float inv = 1.0f / norm;
#pragma unroll
            for (int m = 0; m < NREF; ++m) out[m] = gw[m] * inv;
        } else {
#pragma unroll
            for (int m = 0; m < NREF; ++m) out[m] = (m == bi) ? 1.0f : 0.0f;
        }
        uint4 r;
        r.x = h2bits(__floats2half2_rn(out[0], out[1]));
        r.y = h2bits(__floats2half2_rn(out[2], out[3]));
        r.z = __float_as_uint(r4r2[z]);
        r.w = (unsigned)z;
        wrec[a] = r;
    }
}

// ---------------- Kernel 3: pair energy + reduction (depth-2 gather chain) ----------------
__global__ void energy_kernel(const uint4* __restrict__ erec,
                              const uint4* __restrict__ wrec,
                              const unsigned* __restrict__ tabh,
                              double* __restrict__ acc,
                              int n_edges) {
    double local = 0.0;
    int t = blockIdx.x * blockDim.x + threadIdx.x;
    int lane = threadIdx.x & 63;
    int gwave = t >> 6;
    int nwave = (gridDim.x * blockDim.x) >> 6;
    for (int wb = gwave * 256; wb < n_edges; wb += nwave * 256) {
        int e0 = wb + lane;
        uint4 rec[4];
        bool ok[4];
#pragma unroll
        for (int s = 0; s < 4; ++s) {
            int e = e0 + s * 64;
            ok[s] = (e < n_edges);
            uint4 dead = { __float_as_uint(1e30f), 0u, 0u, 0u };
            rec[s] = ok[s] ? erec[e] : dead;
        }
        // depth-1: wrec gathers AND table gathers issue together (pidx from rec)
        uint4 wri[4], wrj[4];
        uint4 t0[4], t1[4], t2[4];
        unsigned t3[4];
#pragma unroll
        for (int s = 0; s < 4; ++s) {
            unsigned ij = rec[s].y;
            wri[s] = wrec[ij & 0xFFFFu];
            wrj[s] = wrec[ij >> 16];
            const uint4* Tv = (const uint4*)(tabh + (size_t)rec[s].z * (THS / 2));
            t0[s] = Tv[0];
            t1[s] = Tv[1];
            t2[s] = Tv[2];
            t3[s] = ((const unsigned*)Tv)[12];
        }
#pragma unroll
        for (int s = 0; s < 4; ++s) {
            float d = __uint_as_float(rec[s].x);
            if (d < DISP_CUT) {
                float wiv[NREF], wjv[NREF];
                float2 p;
                p = bits2f2(wri[s].x); wiv[0] = p.x; wiv[1] = p.y;
                p = bits2f2(wri[s].y); wiv[2] = p.x; wiv[3] = p.y;
                wiv[4] = 1.0f - (wiv[0] + wiv[1] + wiv[2] + wiv[3]);
                p = bits2f2(wrj[s].x); wjv[0] = p.x; wjv[1] = p.y;
                p = bits2f2(wrj[s].y); wjv[2] = p.x; wjv[3] = p.y;
                wjv[4] = 1.0f - (wjv[0] + wjv[1] + wjv[2] + wjv[3]);
                unsigned us[13] = { t0[s].x, t0[s].y, t0[s].z, t0[s].w,
                                    t1[s].x, t1[s].y, t1[s].z, t1[s].w,
                                    t2[s].x, t2[s].y, t2[s].z, t2[s].w, t3[s] };
                float tt[26];
#pragma unroll
                for (int k = 0; k < 13; ++k) {
                    float2 q = bits2f2(us[k]);
                    tt[2 * k] = q.x;
                    tt[2 * k + 1] = q.y;
                }
                float c6 = 0.0f;
#pragma unroll
                for (int a = 0; a < NREF; ++a) {
                    float sacc = 0.0f;
#pragma unroll
                    for (int b = 0; b < NREF; ++b) sacc += wjv[b] * tt[a * NREF + b];
                    c6 += wiv[a] * sacc;
                }
                float r4i = __uint_as_float(wri[s].z);
                float r4j = __uint_as_float(wrj[s].z);
                float qq = 3.0f * r4i * r4j;
                float c8 = c6 * qq;
                float f = A1C * sqrtf(qq) + A2C;
                float f2 = f * f;
                float f6 = f2 * f2 * f2;
                float f8 = f6 * f2;
                float d2 = d * d;
                float d6 = d2 * d2 * d2;
                float d8 = d6 * d2;
                float e_pair = -(S6C * c6 / (d6 + f6) + S8C * c8 / (d8 + f8));
                local += 0.5 * (double)e_pair;
            }
        }
    }
#pragma unroll
    for (int off = 32; off > 0; off >>= 1) local += __shfl_down(local, off, 64);
    __shared__ double wsum[8];
    int wave = threadIdx.x >> 6;
    if ((threadIdx.x & 63) == 0) wsum[wave] = local;
    __syncthreads();
    if (threadIdx.x == 0) {
        double b = 0.0;
        int nwaves = (blockDim.x + 63) >> 6;
        for (int w = 0; w < nwaves; ++w) b += wsum[w];
        atomicAdd(acc, b);
    }
}

// ---------------- Fallback (small ws or n_atoms > 65535) ----------------
__global__ void cn_kernel_old(const float* __restrict__ pos,
                              const int* __restrict__ numbers,
                              const int* __restrict__ ei,
                              const int* __restrict__ ej,
                              const float* __restrict__ rcov,
                              float* __restrict__ cn,
                              int n_edges) {
    int stride = gridDim.x * blockDim.x;
    for (int e = blockIdx.x * blockDim.x + threadIdx.x; e < n_edges; e += stride) {
        int i = ei[e];
        int j = ej[e];
        float dx = pos[3 * j + 0] - pos[3 * i + 0];
        float dy = pos[3 * j + 1] - pos[3 * i + 1];
        float dz = pos[3 * j + 2] - pos[3 * i + 2];
        float d = sqrtf(dx * dx + dy * dy + dz * dz + 1e-20f);
        if (d < CN_CUT) {
            float rr = rcov[numbers[i]] + rcov[numbers[j]];
            float x = K1C * (K2C * rr / d - 1.0f);
            atomicAdd(&cn[i], 1.0f / (1.0f + expf(-x)));
        }
    }
}

__global__ void weights_kernel_old(const float* __restrict__ cn,
                                   const int* __restrict__ numbers,
                                   const float* __restrict__ cn_ref,
                                   const float* __restrict__ r4r2,
                                   uint4* __restrict__ wrec,
                                   int n_atoms) {
    int stride = gridDim.x * blockDim.x;
    for (int a = blockIdx.x * blockDim.x + threadIdx.x; a < n_atoms; a += stride) {
        int z = numbers[a];
        float c = cn[a];
        float gw[NREF];
        float norm = 0.0f;
        float best = -INFINITY;
        int bi = 0;
#pragma unroll
        for (int m = 0; m < NREF; ++m) {
            float r = cn_ref[z * NREF + m];
            bool valid = (r >= 0.0f);
            float tt = c - r;
            float g = valid ? expf(-K3C * tt * tt) : 0.0f;
            gw[m] = g;
            norm += g;
            if (valid && r > best) { best = r; bi = m; }
        }
        float out[NREF];
        if (norm > 1e-30f) {
            float inv = 1.0f / norm;
#pragma unroll
            for (int m = 0; m < NREF; ++m) out[m] = gw[m] * inv;
        } else {
#pragma unroll
            for (int m = 0; m < NREF; ++m) out[m] = (m == bi) ? 1.0f : 0.0f;
        }
        uint4 r;
        r.x = h2bits(__floats2half2_rn(out[0], out[1]));
        r.y = h2bits(__floats2half2_rn(out[2], out[3]));
        r.z = __float_as_uint(r4r2[z]);
        r.w = (unsigned)z;
        wrec[a] = r;
    }
}

__global__ void energy_kernel_old(const float* __restrict__ pos,
                                  const int* __restrict__ ei,
                                  const int* __restrict__ ej,
                                  const float* __restrict__ c6tab,
                                  const uint4* __restrict__ wrec,
                                  double* __restrict__ acc,
                                  int n_edges) {
    double local = 0.0;
    int stride = gridDim.x * blockDim.x;
    for (int e = blockIdx.x * blockDim.x + threadIdx.x; e < n_edges; e += stride) {
        int i = ei[e];
        int j = ej[e];
        float dx = pos[3 * j + 0] - pos[3 * i + 0];
        float dy = pos[3 * j + 1] - pos[3 * i + 1];
        float dz = pos[3 * j + 2] - pos[3 * i + 2];
        float d = sqrtf(dx * dx + dy * dy + dz * dz + 1e-20f);
        if (d < DISP_CUT) {
            uint4 wi = wrec[i], wj = wrec[j];
            int zi = (int)wi.w, zj = (int)wj.w;
            const float* T = c6tab + ((size_t)(zi * MAXZ + zj)) * 25;
            float wiv[NREF], wjv[NREF];
            float2 p;
            p = bits2f2(wi.x); wiv[0] = p.x; wiv[1] = p.y;
            p = bits2f2(wi.y); wiv[2] = p.x; wiv[3] = p.y;
            wiv[4] = 1.0f - (wiv[0] + wiv[1] + wiv[2] + wiv[3]);
            p = bits2f2(wj.x); wjv[0] = p.x; wjv[1] = p.y;
            p = bits2f2(wj.y); wjv[2] = p.x; wjv[3] = p.y;
            wjv[4] = 1.0f - (wjv[0] + wjv[1] + wjv[2] + wjv[3]);
            float c6 = 0.0f;
#pragma unroll
            for (int a = 0; a < NREF; ++a) {
                float sacc = 0.0f;
#pragma unroll
                for (int b = 0; b < NREF; ++b) sacc += wjv[b] * T[a * NREF + b];
                c6 += wiv[a] * sacc;
            }
            float qq = 3.0f * __uint_as_float(wi.z) * __uint_as_float(wj.z);
            float c8 = c6 * qq;
            float f = A1C * sqrtf(qq) + A2C;
            float f2 = f * f;
            float f6 = f2 * f2 * f2;
            float f8 = f6 * f2;
            float d2 = d * d;
            float d6 = d2 * d2 * d2;
            float d8 = d6 * d2;
            float e_pair = -(S6C * c6 / (d6 + f6) + S8C * c8 / (d8 + f8));
            local += 0.5 * (double)e_pair;
        }
    }
#pragma unroll
    for (int off = 32; off > 0; off >>= 1) local += __shfl_down(local, off, 64);
    __shared__ double wsum[8];
    int wave = threadIdx.x >> 6;
    if ((threadIdx.x & 63) == 0) wsum[wave] = local;
    __syncthreads();
    if (threadIdx.x == 0) {
        double b = 0.0;
        int nwaves = (blockDim.x + 63) >> 6;
        for (int w = 0; w < nwaves; ++w) b += wsum[w];
        atomicAdd(acc, b);
    }
}

// ---------------- finalize ----------------
__global__ void finalize_kernel(const double* __restrict__ acc, float* __restrict__ out) {
    out[0] = (float)acc[0];
}

static inline size_t align16(size_t x) { return (x + 15) & ~(size_t)15; }

extern "C" void kernel_launch(void* const* d_in, const int* in_sizes, int n_in,
                              void* d_out, int out_size, void* d_ws, size_t ws_size,
                              hipStream_t stream) {
    const float* pos     = (const float*)d_in[0];
    const int*   numbers = (const int*)d_in[1];
    const int*   ei      = (const int*)d_in[2];
    const int*   ej      = (const int*)d_in[3];
    const float* rcov    = (const float*)d_in[4];
    const float* r4r2    = (const float*)d_in[5];
    const float* c6tab   = (const float*)d_in[6];
    const float* cn_ref  = (const float*)d_in[7];

    int n_atoms = in_sizes[1];
    int n_edges = in_sizes[2];
    int npad = (n_atoms + 3) & ~3;

    char* ws = (char*)d_ws;
    size_t off = 0;
    float* cn4 = (float*)(ws + off);        off += (size_t)NCN * npad * 4;
    double* acc = (double*)(ws + off);      size_t zero_bytes = off + 16; off += 16;
    uint4* wrec = (uint4*)(ws + off);       off += (size_t)n_atoms * 16;
    size_t small_needed = off;
    f4* posrec = (f4*)(ws + off);           off += (size_t)n_atoms * 16;
    unsigned* tabh = (unsigned*)(ws + off); off += align16((size_t)MAXZ * MAXZ * (THS / 2) * 4);
    uint4* erec = (uint4*)(ws + off);       off += (size_t)n_edges * 16;
    size_t full_needed = off;

    hipMemsetAsync(d_ws, 0, zero_bytes, stream);

    const int block = 256;
    int egrid = (n_edges + block - 1) / block;
    int egrid4 = (n_edges + block * 4 - 1) / (block * 4);
    int agrid = (n_atoms + block - 1) / block;
    int pgrid = ((MAXZ * MAXZ > n_atoms ? MAXZ * MAXZ : n_atoms) + block - 1) / block;

    if (ws_size >= full_needed && n_atoms <= 65535) {
        pack_kernel<<<pgrid, block, 0, stream>>>(pos, numbers, rcov, c6tab,
                                                 posrec, tabh, n_atoms);
        cn_pre_kernel<<<egrid4, block, 0, stream>>>(posrec, ei, ej, cn4, erec,
                                                    n_edges, npad);
        weights_kernel<<<agrid, block, 0, stream>>>(cn4, numbers, cn_ref, r4r2,
                                                    wrec, n_atoms, npad);
        energy_kernel<<<egrid4, block, 0, stream>>>(erec, wrec, tabh, acc, n_edges);
    } else if (ws_size >= small_needed) {
        cn_kernel_old<<<egrid, block, 0, stream>>>(pos, numbers, ei, ej, rcov, cn4, n_edges);
        weights_kernel_old<<<agrid, block, 0, stream>>>(cn4, numbers, cn_ref, r4r2,
                                                        wrec, n_atoms);
        energy_kernel_old<<<egrid, block, 0, stream>>>(pos, ei, ej, c6tab, wrec, acc, n_edges);
    }
    finalize_kernel<<<1, 1, 0, stream>>>(acc, (float*)d_out);
}